// Round 10
// baseline (2391.350 us; speedup 1.0000x reference)
//
#include <hip/hip_runtime.h>
#include <cstdint>

#define T_SNN 20
#define THREADS 1024
#define ROWS 32
#define W2LD 268           // 4*67: b128 reads spread banks; staging conflict-free
#define WMLD 68            // 4*17

__device__ __forceinline__ float rdlane(float v, int i) {
    return __int_as_float(__builtin_amdgcn_readlane(__float_as_int(v), i));
}

__global__ __launch_bounds__(THREADS, 4)
void snn_v10(const float* __restrict__ state,
             const float* __restrict__ W1,
             const float* __restrict__ b1,
             const float* __restrict__ W2,
             const float* __restrict__ b2,
             const float* __restrict__ Wmu,
             const float* __restrict__ bmu,
             const float* __restrict__ Wsig,
             const float* __restrict__ bsig,
             float* __restrict__ out, int B)
{
    __shared__ float z1s  [ROWS * 256];     // 32 KB
    __shared__ float w2lds[64 * W2LD];      // 68.6 KB  w2lds[j*W2LD+i] = W2[j][i]
    __shared__ float wms2 [16 * WMLD];      // 4.4 KB
    __shared__ float bms_s[16];

    const int tid  = threadIdx.x;
    const int row0 = blockIdx.x * ROWS;

    // ---- stage weights ----
    for (int e = tid; e < 64 * 256; e += THREADS) {
        int j = e >> 8, i = e & 255;
        w2lds[j * W2LD + i] = W2[e];
    }
    for (int e = tid; e < 16 * 64; e += THREADS) {
        int q = e >> 6, j = e & 63;
        wms2[q * WMLD + j] = (q < 8) ? Wmu[q * 64 + j] : Wsig[(q - 8) * 64 + j];
    }
    if (tid < 16) bms_s[tid] = (tid < 8) ? bmu[tid] : bsig[tid - 8];

    // ---- phase A: z1 = state @ W1^T + b1, strict ascending-k fma ----
    {
        const int i1 = tid & 255;
        const int h  = __builtin_amdgcn_readfirstlane((int)(threadIdx.x >> 8)); // 0..3
        const float* __restrict__ w1row = W1 + i1 * 256;
        const float* __restrict__ sg = state + (size_t)(row0 + h * 8) * 256;    // uniform
        float acc[8];
        #pragma unroll
        for (int r = 0; r < 8; ++r) acc[r] = 0.f;
        for (int k = 0; k < 256; k += 4) {
            const float4 wv = *reinterpret_cast<const float4*>(w1row + k);
            #pragma unroll
            for (int r = 0; r < 8; ++r) {
                const float4 sv = *reinterpret_cast<const float4*>(sg + r * 256 + k);
                acc[r] = __fmaf_rn(sv.x, wv.x, acc[r]);
                acc[r] = __fmaf_rn(sv.y, wv.y, acc[r]);
                acc[r] = __fmaf_rn(sv.z, wv.z, acc[r]);
                acc[r] = __fmaf_rn(sv.w, wv.w, acc[r]);
            }
        }
        const float bb = b1[i1];
        #pragma unroll
        for (int r = 0; r < 8; ++r)
            z1s[(h * 8 + r) * 256 + i1] = __fadd_rn(acc[r], bb);
    }
    __syncthreads();

    // ---- phase B: 16 waves, 2 rows each (4 waves/SIMD) ----
    const int lane = tid & 63;
    const int wv_  = __builtin_amdgcn_readfirstlane((int)(threadIdx.x >> 6)); // 0..15
    const int rhat = (lane >> 4) & 1;
    const int q    = lane & 15;

    float z1r[2][4], mem1[2][4];
    #pragma unroll
    for (int r = 0; r < 2; ++r)
        #pragma unroll
        for (int c = 0; c < 4; ++c) {
            z1r[r][c]  = z1s[(wv_ * 2 + r) * 256 + c * 64 + lane];
            mem1[r][c] = 0.f;
        }
    float mem2[2] = {0.f, 0.f};
    float m34 = 0.f;
    const float b2j  = b2[lane];
    const float bmsq = bms_s[q];
    const float* __restrict__ wp = &w2lds[lane * W2LD];

    #pragma unroll 1
    for (int t = 0; t < T_SNN; ++t) {
        // ---- L1 LIF (strict np rounding) + spike FLOATS (exactly what np multiplies) ----
        float spkf[2][4];
        #pragma unroll
        for (int r = 0; r < 2; ++r)
            #pragma unroll
            for (int c = 0; c < 4; ++c) {
                float rst = (mem1[r][c] > 1.0f) ? 1.0f : 0.0f;
                float a = __fmul_rn(0.9f, mem1[r][c]);
                a = __fadd_rn(a, z1r[r][c]);
                mem1[r][c] = __fsub_rn(a, rst);
                spkf[r][c] = (mem1[r][c] > 1.0f) ? 1.0f : 0.0f;
            }

        // ---- L2 gather: readlane spike -> SGPR, v_fmac (== oracle's fma(spk,w,acc)) ----
        float acc0 = 0.f, acc1 = 0.f;
        #pragma unroll
        for (int c = 0; c < 4; ++c) {
            float4 wv[16];
            #pragma unroll
            for (int u = 0; u < 16; ++u)
                wv[u] = *reinterpret_cast<const float4*>(wp + c * 64 + u * 4);
            const float s0v = spkf[0][c], s1v = spkf[1][c];
            #pragma unroll
            for (int u = 0; u < 16; ++u) {
                #pragma unroll
                for (int e = 0; e < 4; ++e) {
                    const int i = u * 4 + e;
                    const float w = (e == 0) ? wv[u].x : (e == 1) ? wv[u].y
                                  : (e == 2) ? wv[u].z : wv[u].w;
                    acc0 = __fmaf_rn(w, rdlane(s0v, i), acc0);
                    acc1 = __fmaf_rn(w, rdlane(s1v, i), acc1);
                }
            }
        }

        // ---- L2 LIF + ballots ----
        uint64_t m2[2];
        {
            float z2  = __fadd_rn(acc0, b2j);
            float rst = (mem2[0] > 1.0f) ? 1.0f : 0.0f;
            float a   = __fmul_rn(0.9f, mem2[0]);
            a = __fadd_rn(a, z2);
            mem2[0] = __fsub_rn(a, rst);
            m2[0] = __ballot(mem2[0] > 1.0f);
        }
        {
            float z2  = __fadd_rn(acc1, b2j);
            float rst = (mem2[1] > 1.0f) ? 1.0f : 0.0f;
            float a   = __fmul_rn(0.9f, mem2[1]);
            a = __fadd_rn(a, z2);
            mem2[1] = __fsub_rn(a, rst);
            m2[1] = __ballot(mem2[1] > 1.0f);
        }

        // ---- readout dense-AND (per-lane masks, v_bfe signs) ----
        const uint32_t mlo = rhat ? (uint32_t)m2[1] : (uint32_t)m2[0];
        const uint32_t mhi = rhat ? (uint32_t)(m2[1] >> 32) : (uint32_t)(m2[0] >> 32);
        float accm = 0.f;
        #pragma unroll
        for (int jw = 0; jw < 16; ++jw) {
            const float4 wvv = *reinterpret_cast<const float4*>(&wms2[q * WMLD + jw * 4]);
            #pragma unroll
            for (int e = 0; e < 4; ++e) {
                const int j = jw * 4 + e;
                const uint32_t mw = (j < 32) ? mlo : mhi;
                const uint32_t sg = (uint32_t)__builtin_amdgcn_sbfe(mw, j & 31, 1);
                const float we = (e == 0) ? wvv.x : (e == 1) ? wvv.y : (e == 2) ? wvv.z : wvv.w;
                accm = __fadd_rn(accm, __uint_as_float(__float_as_uint(we) & sg));
            }
        }
        float zm  = __fadd_rn(accm, bmsq);
        float rst = (m34 > 1.0f) ? 1.0f : 0.0f;
        float a   = __fmul_rn(0.9f, m34);
        a = __fadd_rn(a, zm);
        m34 = __fsub_rn(a, rst);
    }

    // ---- epilogue ----
    if (lane < 32) {
        const int row = row0 + wv_ * 2 + rhat;
        if (q < 8) {
            out[row * 8 + q] = (float)tanh((double)m34);
        } else {
            double mv = (double)m34;
            double sp = fmax(mv, 0.0) + log1p(exp(-fabs(mv)));
            double sg = fmin(fmax(sp + 0.03, 0.03), 1.0);
            out[(size_t)B * 8 + row * 8 + (q - 8)] = (float)sg;
        }
    }
}

extern "C" void kernel_launch(void* const* d_in, const int* in_sizes, int n_in,
                              void* d_out, int out_size, void* d_ws, size_t ws_size,
                              hipStream_t stream) {
    const float* state = (const float*)d_in[0];
    const float* W1    = (const float*)d_in[1];
    const float* b1    = (const float*)d_in[2];
    const float* W2    = (const float*)d_in[3];
    const float* b2    = (const float*)d_in[4];
    const float* Wmu   = (const float*)d_in[5];
    const float* bmu   = (const float*)d_in[6];
    const float* Wsig  = (const float*)d_in[7];
    const float* bsig  = (const float*)d_in[8];
    float* out = (float*)d_out;

    const int B = in_sizes[0] / 256;
    hipLaunchKernelGGL(snn_v10, dim3(B / ROWS), dim3(THREADS), 0, stream,
                       state, W1, b1, W2, b2, Wmu, bmu, Wsig, bsig, out, B);
}